// Round 7
// baseline (395.299 us; speedup 1.0000x reference)
//
#include <hip/hip_runtime.h>

typedef unsigned short u16;
typedef __attribute__((ext_vector_type(8))) short bf16x8;
typedef __attribute__((ext_vector_type(4))) float f32x4;
typedef __attribute__((ext_vector_type(8))) unsigned short u16x8;
typedef __attribute__((ext_vector_type(4))) unsigned short u16x4;
typedef __attribute__((ext_vector_type(4))) float f32x4v;

#define LOG2E 1.4426950408889634f
#define QSCALE 0.18033688011112042f  // 0.125 * log2(e)

// B=2, S=2048, D=1024, H=16, HD=64
#define SB 2048
#define DB 1024
#define NH 16
#define HD 64

__device__ __forceinline__ u16 f2bf(float f) {
  unsigned u = __float_as_uint(f);
  return (u16)((u + 0x7FFFu + ((u >> 16) & 1u)) >> 16);
}
__device__ __forceinline__ float bf2f(u16 h) {
  return __uint_as_float(((unsigned)h) << 16);
}
__device__ __forceinline__ unsigned cvt_pk_bf16(float lo, float hi) {
  unsigned r;
  asm("v_cvt_pk_bf16_f32 %0, %1, %2" : "=v"(r) : "v"(lo), "v"(hi));
  return r;
}

__device__ __forceinline__ void gload_lds16(const void* g, void* l) {
  __builtin_amdgcn_global_load_lds((const __attribute__((address_space(1))) void*)g,
                                   (__attribute__((address_space(3))) void*)l, 16, 0, 0);
}

// ---- conversion kernels ----

__global__ void conv_x_kernel(const float* __restrict__ in, u16* __restrict__ out) {
  int i = blockIdx.x * blockDim.x + threadIdx.x;  // each handles 8 elems
  const f32x4v* p = (const f32x4v*)in + (size_t)i * 2;
  f32x4v a = p[0], b = p[1];
  u16x8 o;
  o[0] = f2bf(a[0]); o[1] = f2bf(a[1]); o[2] = f2bf(a[2]); o[3] = f2bf(a[3]);
  o[4] = f2bf(b[0]); o[5] = f2bf(b[1]); o[6] = f2bf(b[2]); o[7] = f2bf(b[3]);
  *((u16x8*)out + i) = o;
}

// transpose W [K][N] -> Wt [N][K] in bf16, z selects Wq/Wk/Wv
__global__ void conv_wt_kernel(const float* __restrict__ Wq, const float* __restrict__ Wk,
                               const float* __restrict__ Wv, u16* __restrict__ Wt) {
  __shared__ float tile[32][33];
  int z = blockIdx.z;
  const float* W = (z == 0) ? Wq : (z == 1) ? Wk : Wv;
  int k0 = blockIdx.x * 32, n0 = blockIdx.y * 32;
  int tx = threadIdx.x;
  for (int i = threadIdx.y; i < 32; i += 8)
    tile[i][tx] = W[(size_t)(k0 + i) * DB + n0 + tx];
  __syncthreads();
  for (int i = threadIdx.y; i < 32; i += 8)
    Wt[(size_t)z * DB * DB + (size_t)(n0 + i) * DB + k0 + tx] = f2bf(tile[tx][i]);
}

// Rearrange bias into per-(b, q-block, k-tile, wave, lane) fragment order, bf16,
// pre-multiplied by coef*LOG2E, with mask folded in.
// value(e) for lane: q = wid*16 + (lane&15), k = (e>>2)*16 + (lane>>4)*4 + (e&3)
__global__ __launch_bounds__(256) void conv_biasr_kernel(
    const float* __restrict__ biasM, const float* __restrict__ coef,
    const float* __restrict__ mask, u16* __restrict__ biasR) {
  __shared__ float tile[64 * 64];
  __shared__ float msh[64];
  int ktb = blockIdx.x, q0b = blockIdx.y, b = blockIdx.z;
  int q0 = q0b * 64, k0 = ktb * 64;
  int tid = threadIdx.x;
  float c = coef[0] * LOG2E;
  for (int i = tid; i < 4096; i += 256)
    tile[i] = biasM[(size_t)(q0 + (i >> 6)) * SB + k0 + (i & 63)];
  if (tid < 64) msh[tid] = mask[b * SB + k0 + tid] * LOG2E;
  __syncthreads();
  int wid = tid >> 6, lane = tid & 63, lrow = lane & 15, lk = lane >> 4;
  int qloc = wid * 16 + lrow;
  u16x8 o0, o1;
#pragma unroll
  for (int e = 0; e < 16; e++) {
    int kloc = (e >> 2) * 16 + lk * 4 + (e & 3);
    float v = tile[qloc * 64 + kloc] * c + msh[kloc];
    if (e < 8) o0[e] = f2bf(v); else o1[e - 8] = f2bf(v);
  }
  size_t base = ((((size_t)b * 32 + q0b) * 32 + ktb) * 4 + wid) * 1024 + lane * 16;
  *(u16x8*)&biasR[base] = o0;
  *(u16x8*)&biasR[base + 8] = o1;
}

// ---- QKV projection GEMM: [4096x1024] x [1024x1024] per z ----
// Q (scaled by 0.125*LOG2E), K: [bh][s][64] bf16 ; V transposed: [bh][64][s]
__global__ __launch_bounds__(256) void gemm_qkv_kernel(
    const u16* __restrict__ X, const u16* __restrict__ Wt,
    const float* __restrict__ bq, const float* __restrict__ bk, const float* __restrict__ bv,
    u16* __restrict__ Q, u16* __restrict__ K, u16* __restrict__ V) {
  __shared__ __align__(16) u16 As[128 * 32];
  __shared__ __align__(16) u16 Bs[128 * 32];
  int z = blockIdx.z;
  const u16* Wz = Wt + (size_t)z * DB * DB;
  const float* bias = (z == 0) ? bq : (z == 1) ? bk : bv;
  int m0 = blockIdx.x * 128, n0 = blockIdx.y * 128;
  int tid = threadIdx.x, wid = tid >> 6, lane = tid & 63;
  int wr = wid >> 1, wc = wid & 1;
  int lrow = lane & 15, lk = lane >> 4;
  int srow = lane >> 2, scol = (lane & 3) * 8;

  f32x4 acc[4][4];
#pragma unroll
  for (int i = 0; i < 4; i++)
#pragma unroll
    for (int j = 0; j < 4; j++) acc[i][j] = (f32x4){0.f, 0.f, 0.f, 0.f};

  for (int k0 = 0; k0 < DB; k0 += 32) {
#pragma unroll
    for (int p = 0; p < 2; p++) {
      int c = p * 4 + wid;
      gload_lds16(X + (size_t)(m0 + c * 16 + srow) * DB + k0 + scol, &As[c * 512]);
      gload_lds16(Wz + (size_t)(n0 + c * 16 + srow) * DB + k0 + scol, &Bs[c * 512]);
    }
    __syncthreads();
    bf16x8 af[4], bf_[4];
#pragma unroll
    for (int i = 0; i < 4; i++)
      af[i] = *(const bf16x8*)&As[(wr * 64 + i * 16 + lrow) * 32 + lk * 8];
#pragma unroll
    for (int j = 0; j < 4; j++)
      bf_[j] = *(const bf16x8*)&Bs[(wc * 64 + j * 16 + lrow) * 32 + lk * 8];
#pragma unroll
    for (int i = 0; i < 4; i++)
#pragma unroll
      for (int j = 0; j < 4; j++)
        acc[i][j] = __builtin_amdgcn_mfma_f32_16x16x32_bf16(af[i], bf_[j], acc[i][j], 0, 0, 0);
    __syncthreads();
  }

  float sc = (z == 0) ? QSCALE : 1.0f;
#pragma unroll
  for (int j = 0; j < 4; j++) {
    int n = n0 + wc * 64 + j * 16 + lrow;
    float bb = bias[n];
    int h = n >> 6, hd = n & 63;
#pragma unroll
    for (int i = 0; i < 4; i++) {
      int mbase = m0 + wr * 64 + i * 16 + lk * 4;
      int b = mbase >> 11;
      int s = mbase & (SB - 1);
      int bh = b * NH + h;
      if (z == 2) {
        u16x4 pk;
#pragma unroll
        for (int r = 0; r < 4; r++) pk[r] = f2bf(acc[i][j][r] + bb);
        *(u16x4*)&V[((size_t)bh * HD + hd) * SB + s] = pk;
      } else {
        u16* dst = (z == 0) ? Q : K;
#pragma unroll
        for (int r = 0; r < 4; r++)
          dst[((size_t)bh * SB + (s + r)) * HD + hd] = f2bf((acc[i][j][r] + bb) * sc);
      }
    }
  }
}

// ---- flash attention (swapped QK^T, no-max softmax, barrier-free) ----
// grid (S/64, B*H); 4 waves x 16 q-rows; KV tile 64
__global__ __launch_bounds__(256) void attn_kernel(
    const u16* __restrict__ Q, const u16* __restrict__ K, const u16* __restrict__ Vt,
    const u16* __restrict__ biasR, float* __restrict__ out) {
  __shared__ __align__(16) u16 P[4][16 * 64];  // per-wave private
  __shared__ float Lsh[4][16];
  int bh = blockIdx.y;
  int b = bh >> 4, h = bh & 15;
  int q0b = blockIdx.x, q0 = q0b * 64;
  int tid = threadIdx.x, wid = tid >> 6, lane = tid & 63;
  int lrow = lane & 15, lk = lane >> 4;
  const u16* Qb = Q + (size_t)bh * SB * HD;
  const u16* Kb = K + (size_t)bh * SB * HD;
  const u16* Vb = Vt + (size_t)bh * HD * SB;
  const u16* biasW = biasR + (size_t)(b * 32 + q0b) * 131072 + wid * 1024 + lane * 16;

  int qr = q0 + wid * 16 + lrow;
  bf16x8 qf0 = *(const bf16x8*)&Qb[(size_t)qr * HD + lk * 8];
  bf16x8 qf1 = *(const bf16x8*)&Qb[(size_t)qr * HD + 32 + lk * 8];

  float l_acc = 0.f;
  f32x4 acc[4];
#pragma unroll
  for (int d = 0; d < 4; d++) acc[d] = (f32x4){0.f, 0.f, 0.f, 0.f};
  u16* Pw = &P[wid][0];

  for (int ktb = 0; ktb < 32; ktb++) {
    int kt = ktb * 64;
    // swapped QK^T: s = mfma(K, Q) -> lane holds q = lrow, k = kb*16 + lk*4 + r
    f32x4 s[4];
#pragma unroll
    for (int kb = 0; kb < 4; kb++) {
      int krow = kt + kb * 16 + lrow;
      bf16x8 ka0 = *(const bf16x8*)&Kb[(size_t)krow * HD + lk * 8];
      bf16x8 ka1 = *(const bf16x8*)&Kb[(size_t)krow * HD + 32 + lk * 8];
      f32x4 t = __builtin_amdgcn_mfma_f32_16x16x32_bf16(ka0, qf0, (f32x4){0.f, 0.f, 0.f, 0.f}, 0, 0, 0);
      s[kb] = __builtin_amdgcn_mfma_f32_16x16x32_bf16(ka1, qf1, t, 0, 0, 0);
    }
    // bias (pre-scaled by LOG2E, mask folded): 2 coalesced 16B loads
    const u16x8* bp = (const u16x8*)(biasW + (size_t)ktb * 4096);
    u16x8 bv0 = bp[0], bv1 = bp[1];
    // exp (no max subtraction), per-lane l accumulate, pack, LDS write
#pragma unroll
    for (int kb = 0; kb < 4; kb++) {
      float pv[4];
#pragma unroll
      for (int r = 0; r < 4; r++) {
        int e = kb * 4 + r;
        float bb = bf2f(e < 8 ? bv0[e] : bv1[e - 8]);
        pv[r] = exp2f(s[kb][r] + bb);
        l_acc += pv[r];
      }
      unsigned d0 = cvt_pk_bf16(pv[0], pv[1]);
      unsigned d1 = cvt_pk_bf16(pv[2], pv[3]);
      int byte = (lrow * 128 + kb * 32 + lk * 8) ^ ((lrow & 7) << 4);
      *(uint2*)((char*)Pw + byte) = make_uint2(d0, d1);
    }
    asm volatile("s_waitcnt lgkmcnt(0)" ::: "memory");
    // PV: A = P from LDS (row=q=lrow, k=lk*8+e), B = V from global
    bf16x8 pa[2];
#pragma unroll
    for (int ks = 0; ks < 2; ks++) {
      int byte = (lrow * 128 + ks * 64 + lk * 16) ^ ((lrow & 7) << 4);
      pa[ks] = *(const bf16x8*)((char*)Pw + byte);
    }
#pragma unroll
    for (int db = 0; db < 4; db++) {
#pragma unroll
      for (int ks = 0; ks < 2; ks++) {
        bf16x8 vb = *(const bf16x8*)&Vb[(size_t)(db * 16 + lrow) * SB + kt + ks * 32 + lk * 8];
        acc[db] = __builtin_amdgcn_mfma_f32_16x16x32_bf16(pa[ks], vb, acc[db], 0, 0, 0);
      }
    }
  }
  // final l: reduce over the 4 lk-groups (lanes ±16, ±32), bounce via LDS
  l_acc += __shfl_xor(l_acc, 16);
  l_acc += __shfl_xor(l_acc, 32);
  if (lk == 0) Lsh[wid][lrow] = l_acc;
  asm volatile("s_waitcnt lgkmcnt(0)" ::: "memory");
  f32x4v lv = *(const f32x4v*)&Lsh[wid][lk * 4];
  // epilogue: lane holds D[q = lk*4 + r][d = db*16 + lrow]
#pragma unroll
  for (int db = 0; db < 4; db++) {
#pragma unroll
    for (int r = 0; r < 4; r++) {
      int qg = q0 + wid * 16 + lk * 4 + r;
      out[((size_t)b * SB + qg) * DB + h * HD + db * 16 + lrow] = acc[db][r] / lv[r];
    }
  }
}

extern "C" void kernel_launch(void* const* d_in, const int* in_sizes, int n_in,
                              void* d_out, int out_size, void* d_ws, size_t ws_size,
                              hipStream_t stream) {
  const float* hs    = (const float*)d_in[0];
  const float* mask  = (const float*)d_in[1];
  const float* biasM = (const float*)d_in[2];
  const float* coef  = (const float*)d_in[3];
  const float* Wq    = (const float*)d_in[4];
  const float* bq    = (const float*)d_in[5];
  const float* Wk    = (const float*)d_in[6];
  const float* bk    = (const float*)d_in[7];
  const float* Wv    = (const float*)d_in[8];
  const float* bv    = (const float*)d_in[9];
  float* out = (float*)d_out;

  // workspace layout (40 MB): biasR overlaps X/Wt (biasR written after gemm)
  char* w = (char*)d_ws;
  u16* Qb    = (u16*)(w);                       // [32][2048][64]  (8 MB)
  u16* Kb    = (u16*)(w + 8u * 1024 * 1024);    // [32][2048][64]  (8 MB)
  u16* Vb    = (u16*)(w + 16u * 1024 * 1024);   // [32][64][2048]  (8 MB)
  u16* X     = (u16*)(w + 24u * 1024 * 1024);   // 4096x1024 bf16  (8 MB)
  u16* Wt    = (u16*)(w + 32u * 1024 * 1024);   // 3x1024x1024     (6 MB)
  u16* biasR = (u16*)(w + 24u * 1024 * 1024);   // [2][32][32][4][64][16] (16 MB)

  conv_x_kernel<<<2048, 256, 0, stream>>>(hs, X);
  conv_wt_kernel<<<dim3(32, 32, 3), dim3(32, 8), 0, stream>>>(Wq, Wk, Wv, Wt);
  gemm_qkv_kernel<<<dim3(32, 8, 3), 256, 0, stream>>>(X, Wt, bq, bk, bv, Qb, Kb, Vb);
  conv_biasr_kernel<<<dim3(32, 32, 2), 256, 0, stream>>>(biasM, coef, mask, biasR);
  attn_kernel<<<dim3(32, 32), 256, 0, stream>>>(Qb, Kb, Vb, biasR, out);
}

// Round 9
// 232.935 us; speedup vs baseline: 1.6970x; 1.6970x over previous
//
#include <hip/hip_runtime.h>

typedef unsigned short u16;
typedef __attribute__((ext_vector_type(8))) short bf16x8;
typedef __attribute__((ext_vector_type(4))) float f32x4;
typedef __attribute__((ext_vector_type(8))) unsigned short u16x8;
typedef __attribute__((ext_vector_type(4))) unsigned short u16x4;
typedef __attribute__((ext_vector_type(4))) float f32x4v;

#define LOG2E 1.4426950408889634f
#define QSCALE 0.18033688011112042f  // 0.125 * log2(e)

// B=2, S=2048, D=1024, H=16, HD=64
#define SB 2048
#define DB 1024
#define NH 16
#define HD 64

__device__ __forceinline__ u16 f2bf(float f) {
  unsigned u = __float_as_uint(f);
  return (u16)((u + 0x7FFFu + ((u >> 16) & 1u)) >> 16);
}
__device__ __forceinline__ float bf2f(u16 h) {
  return __uint_as_float(((unsigned)h) << 16);
}
__device__ __forceinline__ unsigned cvt_pk_bf16(float lo, float hi) {
  unsigned r;
  asm("v_cvt_pk_bf16_f32 %0, %1, %2" : "=v"(r) : "v"(lo), "v"(hi));
  return r;
}

__device__ __forceinline__ void gload_lds16(const void* g, void* l) {
  __builtin_amdgcn_global_load_lds((const __attribute__((address_space(1))) void*)g,
                                   (__attribute__((address_space(3))) void*)l, 16, 0, 0);
}

// ---- conversion kernels ----

__global__ void conv_x_kernel(const float* __restrict__ in, u16* __restrict__ out) {
  int i = blockIdx.x * blockDim.x + threadIdx.x;  // each handles 8 elems
  const f32x4v* p = (const f32x4v*)in + (size_t)i * 2;
  f32x4v a = p[0], b = p[1];
  u16x8 o;
  o[0] = f2bf(a[0]); o[1] = f2bf(a[1]); o[2] = f2bf(a[2]); o[3] = f2bf(a[3]);
  o[4] = f2bf(b[0]); o[5] = f2bf(b[1]); o[6] = f2bf(b[2]); o[7] = f2bf(b[3]);
  *((u16x8*)out + i) = o;
}

// transpose W [K][N] -> Wt [N][K] in bf16, z selects Wq/Wk/Wv
__global__ void conv_wt_kernel(const float* __restrict__ Wq, const float* __restrict__ Wk,
                               const float* __restrict__ Wv, u16* __restrict__ Wt) {
  __shared__ float tile[32][33];
  int z = blockIdx.z;
  const float* W = (z == 0) ? Wq : (z == 1) ? Wk : Wv;
  int k0 = blockIdx.x * 32, n0 = blockIdx.y * 32;
  int tx = threadIdx.x;
  for (int i = threadIdx.y; i < 32; i += 8)
    tile[i][tx] = W[(size_t)(k0 + i) * DB + n0 + tx];
  __syncthreads();
  for (int i = threadIdx.y; i < 32; i += 8)
    Wt[(size_t)z * DB * DB + (size_t)(n0 + i) * DB + k0 + tx] = f2bf(tile[tx][i]);
}

// Bias rearranged for attn (QBLK=128, 8 waves): bf16, pre-scaled by coef*LOG2E,
// mask folded in. Layout [b][q0b:16][ktb:32][wid:8][lane:64][16].
// For wave wid', lane: q = q0b*128 + wid'*16 + (lane&15),
//                      k = ktb*64 + (e>>2)*16 + (lane>>4)*4 + (e&3)
__global__ __launch_bounds__(256) void conv_biasr_kernel(
    const float* __restrict__ biasM, const float* __restrict__ coef,
    const float* __restrict__ mask, u16* __restrict__ biasR) {
  __shared__ float tile[64 * 64];
  __shared__ float msh[64];
  int ktb = blockIdx.x, q64b = blockIdx.y, b = blockIdx.z;
  int q0 = q64b * 64, k0 = ktb * 64;
  int tid = threadIdx.x;
  float c = coef[0] * LOG2E;
  for (int i = tid; i < 4096; i += 256)
    tile[i] = biasM[(size_t)(q0 + (i >> 6)) * SB + k0 + (i & 63)];
  if (tid < 64) msh[tid] = mask[b * SB + k0 + tid] * LOG2E;
  __syncthreads();
  int wid = tid >> 6, lane = tid & 63, lrow = lane & 15, lk = lane >> 4;
  int qloc = wid * 16 + lrow;
  u16x8 o0, o1;
#pragma unroll
  for (int e = 0; e < 16; e++) {
    int kloc = (e >> 2) * 16 + lk * 4 + (e & 3);
    float v = tile[qloc * 64 + kloc] * c + msh[kloc];
    if (e < 8) o0[e] = f2bf(v); else o1[e - 8] = f2bf(v);
  }
  int widp = (q64b & 1) * 4 + wid;  // wave id within the 128-row attn block
  size_t base = ((((size_t)b * 16 + (q64b >> 1)) * 32 + ktb) * 8 + widp) * 1024 + lane * 16;
  *(u16x8*)&biasR[base] = o0;
  *(u16x8*)&biasR[base + 8] = o1;
}

// ---- QKV projection GEMM: [4096x1024] x [1024x1024] per z ----
// Q (scaled by 0.125*LOG2E): [bh][s][64] plain.
// K: [bh][s][64] with per-64-row-tile XOR swizzle: col' = hd ^ ((s&7)<<3)
// V: [bh][64][2048] (d-major) with per-64-col-tile swizzle: kloc' = kloc ^ ((hd&7)<<3)
__global__ __launch_bounds__(256) void gemm_qkv_kernel(
    const u16* __restrict__ X, const u16* __restrict__ Wt,
    const float* __restrict__ bq, const float* __restrict__ bk, const float* __restrict__ bv,
    u16* __restrict__ Q, u16* __restrict__ K, u16* __restrict__ V) {
  __shared__ __align__(16) u16 As[128 * 32];
  __shared__ __align__(16) u16 Bs[128 * 32];
  int z = blockIdx.z;
  const u16* Wz = Wt + (size_t)z * DB * DB;
  const float* bias = (z == 0) ? bq : (z == 1) ? bk : bv;
  int m0 = blockIdx.x * 128, n0 = blockIdx.y * 128;
  int tid = threadIdx.x, wid = tid >> 6, lane = tid & 63;
  int wr = wid >> 1, wc = wid & 1;
  int lrow = lane & 15, lk = lane >> 4;
  int srow = lane >> 2, scol = (lane & 3) * 8;

  f32x4 acc[4][4];
#pragma unroll
  for (int i = 0; i < 4; i++)
#pragma unroll
    for (int j = 0; j < 4; j++) acc[i][j] = (f32x4){0.f, 0.f, 0.f, 0.f};

  for (int k0 = 0; k0 < DB; k0 += 32) {
#pragma unroll
    for (int p = 0; p < 2; p++) {
      int c = p * 4 + wid;
      gload_lds16(X + (size_t)(m0 + c * 16 + srow) * DB + k0 + scol, &As[c * 512]);
      gload_lds16(Wz + (size_t)(n0 + c * 16 + srow) * DB + k0 + scol, &Bs[c * 512]);
    }
    __syncthreads();
    bf16x8 af[4], bf_[4];
#pragma unroll
    for (int i = 0; i < 4; i++)
      af[i] = *(const bf16x8*)&As[(wr * 64 + i * 16 + lrow) * 32 + lk * 8];
#pragma unroll
    for (int j = 0; j < 4; j++)
      bf_[j] = *(const bf16x8*)&Bs[(wc * 64 + j * 16 + lrow) * 32 + lk * 8];
#pragma unroll
    for (int i = 0; i < 4; i++)
#pragma unroll
      for (int j = 0; j < 4; j++)
        acc[i][j] = __builtin_amdgcn_mfma_f32_16x16x32_bf16(af[i], bf_[j], acc[i][j], 0, 0, 0);
    __syncthreads();
  }

#pragma unroll
  for (int j = 0; j < 4; j++) {
    int n = n0 + wc * 64 + j * 16 + lrow;
    float bb = bias[n];
    int h = n >> 6, hd = n & 63;
#pragma unroll
    for (int i = 0; i < 4; i++) {
      int mbase = m0 + wr * 64 + i * 16 + lk * 4;
      int b = mbase >> 11;
      int s = mbase & (SB - 1);
      int bh = b * NH + h;
      if (z == 2) {
        u16x4 pk;
#pragma unroll
        for (int r = 0; r < 4; r++) pk[r] = f2bf(acc[i][j][r] + bb);
        size_t idx = ((size_t)bh * HD + hd) * SB + (s & ~63) + (((s & 63)) ^ ((hd & 7) << 3));
        *(u16x4*)&V[idx] = pk;
      } else if (z == 1) {
#pragma unroll
        for (int r = 0; r < 4; r++) {
          int sr = s + r;
          K[((size_t)bh * SB + sr) * HD + (hd ^ ((sr & 7) << 3))] = f2bf(acc[i][j][r] + bb);
        }
      } else {
#pragma unroll
        for (int r = 0; r < 4; r++)
          Q[((size_t)bh * SB + (s + r)) * HD + hd] = f2bf((acc[i][j][r] + bb) * QSCALE);
      }
    }
  }
}

// ---- flash attention: QBLK=128, 8 waves, K/V LDS-staged (dbuf), swapped QK^T,
// no-max softmax, bias prefetch ----
// grid (NH, B*16); block 512
__global__ __launch_bounds__(512) void attn_kernel(
    const u16* __restrict__ Q, const u16* __restrict__ K, const u16* __restrict__ Vt,
    const u16* __restrict__ biasR, float* __restrict__ out) {
  __shared__ __align__(16) u16 Klds[2][4096];  // [buf][64 rows x 64 cols] swizzled
  __shared__ __align__(16) u16 Vlds[2][4096];  // [buf][64 d x 64 k] swizzled
  __shared__ __align__(16) u16 P[8][1024];     // per-wave private
  __shared__ float Lsh[8][16];
  int h = blockIdx.x;
  int b = blockIdx.y >> 4, q0b = blockIdx.y & 15;
  int bh = b * NH + h;
  int q0 = q0b * 128;
  int tid = threadIdx.x, wid = tid >> 6, lane = tid & 63;
  int lrow = lane & 15, lk = lane >> 4;
  const u16* Qb = Q + (size_t)bh * SB * HD;
  const u16* Kb = K + (size_t)bh * SB * HD;
  const u16* Vb = Vt + (size_t)bh * HD * SB;
  const u16* biasW = biasR + ((((size_t)b * 16 + q0b) * 32) * 8 + wid) * 1024 + lane * 16;

  int qr = q0 + wid * 16 + lrow;
  bf16x8 qf0 = *(const bf16x8*)&Qb[(size_t)qr * HD + lk * 8];
  bf16x8 qf1 = *(const bf16x8*)&Qb[(size_t)qr * HD + 32 + lk * 8];

  // staging source offsets (per lane)
  int kst = wid * 512 + lane * 8;                       // u16 offset into contiguous K tile
  int vrow_st = wid * 8 + (lane >> 3), vslot = lane & 7;  // V: row d, 16B slot

  float l_acc = 0.f;
  f32x4 acc[4];
#pragma unroll
  for (int d = 0; d < 4; d++) acc[d] = (f32x4){0.f, 0.f, 0.f, 0.f};
  u16* Pw = &P[wid][0];

  // prologue: stage tile 0 into buf 0
  gload_lds16(Kb + kst, &Klds[0][wid * 512]);
  gload_lds16(Vb + (size_t)vrow_st * SB + vslot * 8, &Vlds[0][wid * 512]);
  u16x8 bc0 = *(const u16x8*)biasW;
  u16x8 bc1 = *(const u16x8*)(biasW + 8);
  __syncthreads();

  for (int ktb = 0; ktb < 32; ktb++) {
    int cur = ktb & 1;
    if (ktb < 31) {
      int ktn = (ktb + 1) * 64;
      gload_lds16(Kb + (size_t)ktn * HD + kst, &Klds[cur ^ 1][wid * 512]);
      gload_lds16(Vb + (size_t)vrow_st * SB + ktn + vslot * 8, &Vlds[cur ^ 1][wid * 512]);
    }
    // prefetch next tile's bias
    int ktp = (ktb + 1) & 31;
    u16x8 bn0 = *(const u16x8*)(biasW + (size_t)ktp * 8192);
    u16x8 bn1 = *(const u16x8*)(biasW + (size_t)ktp * 8192 + 8);

    // swapped QK^T from Klds[cur]: lane holds q = lrow, k = kb*16 + lk*4 + r
    f32x4 s[4];
#pragma unroll
    for (int kb = 0; kb < 4; kb++) {
      int krow = kb * 16 + lrow;
      int sw = (krow & 7) << 3;
      bf16x8 ka0 = *(const bf16x8*)&Klds[cur][krow * 64 + ((lk * 8) ^ sw)];
      bf16x8 ka1 = *(const bf16x8*)&Klds[cur][krow * 64 + ((32 + lk * 8) ^ sw)];
      f32x4 t = __builtin_amdgcn_mfma_f32_16x16x32_bf16(ka0, qf0, (f32x4){0.f, 0.f, 0.f, 0.f}, 0, 0, 0);
      s[kb] = __builtin_amdgcn_mfma_f32_16x16x32_bf16(ka1, qf1, t, 0, 0, 0);
    }
    // exp (no max subtraction), per-lane l accumulate, pack, LDS write
#pragma unroll
    for (int kb = 0; kb < 4; kb++) {
      float pv[4];
#pragma unroll
      for (int r = 0; r < 4; r++) {
        int e = kb * 4 + r;
        float bb = bf2f(e < 8 ? bc0[e] : bc1[e - 8]);
        pv[r] = exp2f(s[kb][r] + bb);
        l_acc += pv[r];
      }
      unsigned d0 = cvt_pk_bf16(pv[0], pv[1]);
      unsigned d1 = cvt_pk_bf16(pv[2], pv[3]);
      int byte = (lrow * 128 + kb * 32 + lk * 8) ^ ((lrow & 7) << 4);
      *(uint2*)((char*)Pw + byte) = make_uint2(d0, d1);
    }
    bc0 = bn0; bc1 = bn1;
    asm volatile("s_waitcnt lgkmcnt(0)" ::: "memory");
    // PV: A = P from LDS (row=q=lrow), B = V from Vlds[cur]
    bf16x8 pa[2];
#pragma unroll
    for (int ks = 0; ks < 2; ks++) {
      int byte = (lrow * 128 + ks * 64 + lk * 16) ^ ((lrow & 7) << 4);
      pa[ks] = *(const bf16x8*)((char*)Pw + byte);
    }
#pragma unroll
    for (int db = 0; db < 4; db++) {
      int vrow = db * 16 + lrow;
      int sw = (vrow & 7) << 3;
#pragma unroll
      for (int ks = 0; ks < 2; ks++) {
        bf16x8 vb = *(const bf16x8*)&Vlds[cur][vrow * 64 + ((ks * 32 + lk * 8) ^ sw)];
        acc[db] = __builtin_amdgcn_mfma_f32_16x16x32_bf16(pa[ks], vb, acc[db], 0, 0, 0);
      }
    }
    __syncthreads();
  }
  // final l: reduce over the 4 lk-groups, bounce via LDS
  l_acc += __shfl_xor(l_acc, 16);
  l_acc += __shfl_xor(l_acc, 32);
  if (lk == 0) Lsh[wid][lrow] = l_acc;
  asm volatile("s_waitcnt lgkmcnt(0)" ::: "memory");
  f32x4v lv = *(const f32x4v*)&Lsh[wid][lk * 4];
  // epilogue: lane holds D[q = lk*4 + r][d = db*16 + lrow]
#pragma unroll
  for (int db = 0; db < 4; db++) {
#pragma unroll
    for (int r = 0; r < 4; r++) {
      int qg = q0 + wid * 16 + lk * 4 + r;
      out[((size_t)b * SB + qg) * DB + h * HD + db * 16 + lrow] = acc[db][r] / lv[r];
    }
  }
}

extern "C" void kernel_launch(void* const* d_in, const int* in_sizes, int n_in,
                              void* d_out, int out_size, void* d_ws, size_t ws_size,
                              hipStream_t stream) {
  const float* hs    = (const float*)d_in[0];
  const float* mask  = (const float*)d_in[1];
  const float* biasM = (const float*)d_in[2];
  const float* coef  = (const float*)d_in[3];
  const float* Wq    = (const float*)d_in[4];
  const float* bq    = (const float*)d_in[5];
  const float* Wk    = (const float*)d_in[6];
  const float* bk    = (const float*)d_in[7];
  const float* Wv    = (const float*)d_in[8];
  const float* bv    = (const float*)d_in[9];
  float* out = (float*)d_out;

  // workspace layout (40 MB): biasR overlaps X/Wt (biasR written after gemm)
  char* w = (char*)d_ws;
  u16* Qb    = (u16*)(w);                       // [32][2048][64]  (8 MB)
  u16* Kb    = (u16*)(w + 8u * 1024 * 1024);    // [32][2048][64] swizzled (8 MB)
  u16* Vb    = (u16*)(w + 16u * 1024 * 1024);   // [32][64][2048] swizzled (8 MB)
  u16* X     = (u16*)(w + 24u * 1024 * 1024);   // 4096x1024 bf16  (8 MB)
  u16* Wt    = (u16*)(w + 32u * 1024 * 1024);   // 3x1024x1024     (6 MB)
  u16* biasR = (u16*)(w + 24u * 1024 * 1024);   // [2][16][32][8][64][16] (16 MB)

  conv_x_kernel<<<2048, 256, 0, stream>>>(hs, X);
  conv_wt_kernel<<<dim3(32, 32, 3), dim3(32, 8), 0, stream>>>(Wq, Wk, Wv, Wt);
  gemm_qkv_kernel<<<dim3(32, 8, 3), 256, 0, stream>>>(X, Wt, bq, bk, bv, Qb, Kb, Vb);
  conv_biasr_kernel<<<dim3(32, 32, 2), 256, 0, stream>>>(biasM, coef, mask, biasR);
  attn_kernel<<<dim3(NH, 32), 512, 0, stream>>>(Qb, Kb, Vb, biasR, out);
}

// Round 10
// 227.216 us; speedup vs baseline: 1.7398x; 1.0252x over previous
//
#include <hip/hip_runtime.h>

typedef unsigned short u16;
typedef __attribute__((ext_vector_type(8))) short bf16x8;
typedef __attribute__((ext_vector_type(4))) float f32x4;
typedef __attribute__((ext_vector_type(8))) unsigned short u16x8;
typedef __attribute__((ext_vector_type(4))) unsigned short u16x4;
typedef __attribute__((ext_vector_type(4))) float f32x4v;

#define LOG2E 1.4426950408889634f
#define QSCALE 0.18033688011112042f  // 0.125 * log2(e)

// B=2, S=2048, D=1024, H=16, HD=64
#define SB 2048
#define DB 1024
#define NH 16
#define HD 64

__device__ __forceinline__ u16 f2bf(float f) {
  unsigned u = __float_as_uint(f);
  return (u16)((u + 0x7FFFu + ((u >> 16) & 1u)) >> 16);
}
__device__ __forceinline__ float bf2f(u16 h) {
  return __uint_as_float(((unsigned)h) << 16);
}
__device__ __forceinline__ unsigned cvt_pk_bf16(float lo, float hi) {
  unsigned r;
  asm("v_cvt_pk_bf16_f32 %0, %1, %2" : "=v"(r) : "v"(lo), "v"(hi));
  return r;
}

__device__ __forceinline__ void gload_lds16(const void* g, void* l) {
  __builtin_amdgcn_global_load_lds((const __attribute__((address_space(1))) void*)g,
                                   (__attribute__((address_space(3))) void*)l, 16, 0, 0);
}

// ---- conversion kernels ----

__global__ void conv_x_kernel(const float* __restrict__ in, u16* __restrict__ out) {
  int i = blockIdx.x * blockDim.x + threadIdx.x;  // each handles 8 elems
  const f32x4v* p = (const f32x4v*)in + (size_t)i * 2;
  f32x4v a = p[0], b = p[1];
  u16x8 o;
  o[0] = f2bf(a[0]); o[1] = f2bf(a[1]); o[2] = f2bf(a[2]); o[3] = f2bf(a[3]);
  o[4] = f2bf(b[0]); o[5] = f2bf(b[1]); o[6] = f2bf(b[2]); o[7] = f2bf(b[3]);
  *((u16x8*)out + i) = o;
}

// transpose W [K][N] -> Wt [N][K] in bf16, z selects Wq/Wk/Wv
__global__ void conv_wt_kernel(const float* __restrict__ Wq, const float* __restrict__ Wk,
                               const float* __restrict__ Wv, u16* __restrict__ Wt) {
  __shared__ float tile[32][33];
  int z = blockIdx.z;
  const float* W = (z == 0) ? Wq : (z == 1) ? Wk : Wv;
  int k0 = blockIdx.x * 32, n0 = blockIdx.y * 32;
  int tx = threadIdx.x;
  for (int i = threadIdx.y; i < 32; i += 8)
    tile[i][tx] = W[(size_t)(k0 + i) * DB + n0 + tx];
  __syncthreads();
  for (int i = threadIdx.y; i < 32; i += 8)
    Wt[(size_t)z * DB * DB + (size_t)(n0 + i) * DB + k0 + tx] = f2bf(tile[tx][i]);
}

// Bias rearranged for attn (QBLK=128, 8 waves): bf16, pre-scaled by coef*LOG2E,
// mask folded in. Layout [b][q0b:16][ktb:32][wid:8][lane:64][16].
__global__ __launch_bounds__(256) void conv_biasr_kernel(
    const float* __restrict__ biasM, const float* __restrict__ coef,
    const float* __restrict__ mask, u16* __restrict__ biasR) {
  __shared__ float tile[64 * 64];
  __shared__ float msh[64];
  int ktb = blockIdx.x, q64b = blockIdx.y, b = blockIdx.z;
  int q0 = q64b * 64, k0 = ktb * 64;
  int tid = threadIdx.x;
  float c = coef[0] * LOG2E;
  for (int i = tid; i < 4096; i += 256)
    tile[i] = biasM[(size_t)(q0 + (i >> 6)) * SB + k0 + (i & 63)];
  if (tid < 64) msh[tid] = mask[b * SB + k0 + tid] * LOG2E;
  __syncthreads();
  int wid = tid >> 6, lane = tid & 63, lrow = lane & 15, lk = lane >> 4;
  int qloc = wid * 16 + lrow;
  u16x8 o0, o1;
#pragma unroll
  for (int e = 0; e < 16; e++) {
    int kloc = (e >> 2) * 16 + lk * 4 + (e & 3);
    float v = tile[qloc * 64 + kloc] * c + msh[kloc];
    if (e < 8) o0[e] = f2bf(v); else o1[e - 8] = f2bf(v);
  }
  int widp = (q64b & 1) * 4 + wid;
  size_t base = ((((size_t)b * 16 + (q64b >> 1)) * 32 + ktb) * 8 + widp) * 1024 + lane * 16;
  *(u16x8*)&biasR[base] = o0;
  *(u16x8*)&biasR[base + 8] = o1;
}

// ---- Q/K projection GEMM (z = blockIdx.z: 0=Q, 1=K) ----
// Swapped MFMA operands -> lane holds 4 contiguous hd for one s -> u16x4 stores.
// Q scaled by QSCALE, plain [bh][s][64]. K swizzled: hd' = hd ^ ((s&7)<<3).
__global__ __launch_bounds__(256) void gemm_qk_kernel(
    const u16* __restrict__ X, const u16* __restrict__ Wt,
    const float* __restrict__ bq, const float* __restrict__ bk,
    u16* __restrict__ Q, u16* __restrict__ K) {
  __shared__ __align__(16) u16 As[128 * 32];
  __shared__ __align__(16) u16 Bs[128 * 32];
  int z = blockIdx.z;
  const u16* Wz = Wt + (size_t)z * DB * DB;
  const float* bias = (z == 0) ? bq : bk;
  u16* dst = (z == 0) ? Q : K;
  int m0 = blockIdx.x * 128, n0 = blockIdx.y * 128;
  int tid = threadIdx.x, wid = tid >> 6, lane = tid & 63;
  int wr = wid >> 1, wc = wid & 1;
  int lrow = lane & 15, lk = lane >> 4;
  int srow = lane >> 2, scol = (lane & 3) * 8;

  f32x4 acc[4][4];
#pragma unroll
  for (int i = 0; i < 4; i++)
#pragma unroll
    for (int j = 0; j < 4; j++) acc[i][j] = (f32x4){0.f, 0.f, 0.f, 0.f};

  for (int k0 = 0; k0 < DB; k0 += 32) {
#pragma unroll
    for (int p = 0; p < 2; p++) {
      int c = p * 4 + wid;
      gload_lds16(X + (size_t)(m0 + c * 16 + srow) * DB + k0 + scol, &As[c * 512]);
      gload_lds16(Wz + (size_t)(n0 + c * 16 + srow) * DB + k0 + scol, &Bs[c * 512]);
    }
    __syncthreads();
    bf16x8 af[4], bf_[4];
#pragma unroll
    for (int i = 0; i < 4; i++)
      af[i] = *(const bf16x8*)&As[(wr * 64 + i * 16 + lrow) * 32 + lk * 8];
#pragma unroll
    for (int j = 0; j < 4; j++)
      bf_[j] = *(const bf16x8*)&Bs[(wc * 64 + j * 16 + lrow) * 32 + lk * 8];
#pragma unroll
    for (int i = 0; i < 4; i++)
#pragma unroll
      for (int j = 0; j < 4; j++)
        acc[i][j] = __builtin_amdgcn_mfma_f32_16x16x32_bf16(bf_[j], af[i], acc[i][j], 0, 0, 0);
    __syncthreads();
  }

  // lane holds D[n = n0+wc*64+j*16+lk*4+r][m = m0+wr*64+i*16+lrow]
  int h = (n0 >> 6) + wc;
#pragma unroll
  for (int j = 0; j < 4; j++) {
    int nb = wc * 64 + j * 16 + lk * 4;
    f32x4v bb4 = *(const f32x4v*)&bias[n0 + nb];
    int hd0 = nb & 63;
#pragma unroll
    for (int i = 0; i < 4; i++) {
      int m = m0 + wr * 64 + i * 16 + lrow;
      int b = m >> 11, s = m & (SB - 1);
      int bh = b * NH + h;
      u16x4 pk;
      if (z == 0) {
#pragma unroll
        for (int r = 0; r < 4; r++) pk[r] = f2bf((acc[i][j][r] + bb4[r]) * QSCALE);
        *(u16x4*)&dst[((size_t)bh * SB + s) * HD + hd0] = pk;
      } else {
#pragma unroll
        for (int r = 0; r < 4; r++) pk[r] = f2bf(acc[i][j][r] + bb4[r]);
        *(u16x4*)&dst[((size_t)bh * SB + s) * HD + (hd0 ^ ((s & 7) << 3))] = pk;
      }
    }
  }
}

// ---- V projection GEMM ----
// V: [bh][64][2048] (d-major), swizzled: s' = (s&~63) + ((s&63) ^ ((hd&7)<<3))
__global__ __launch_bounds__(256) void gemm_v_kernel(
    const u16* __restrict__ X, const u16* __restrict__ Wt,
    const float* __restrict__ bv, u16* __restrict__ V) {
  __shared__ __align__(16) u16 As[128 * 32];
  __shared__ __align__(16) u16 Bs[128 * 32];
  const u16* Wz = Wt + (size_t)2 * DB * DB;
  int m0 = blockIdx.x * 128, n0 = blockIdx.y * 128;
  int tid = threadIdx.x, wid = tid >> 6, lane = tid & 63;
  int wr = wid >> 1, wc = wid & 1;
  int lrow = lane & 15, lk = lane >> 4;
  int srow = lane >> 2, scol = (lane & 3) * 8;

  f32x4 acc[4][4];
#pragma unroll
  for (int i = 0; i < 4; i++)
#pragma unroll
    for (int j = 0; j < 4; j++) acc[i][j] = (f32x4){0.f, 0.f, 0.f, 0.f};

  for (int k0 = 0; k0 < DB; k0 += 32) {
#pragma unroll
    for (int p = 0; p < 2; p++) {
      int c = p * 4 + wid;
      gload_lds16(X + (size_t)(m0 + c * 16 + srow) * DB + k0 + scol, &As[c * 512]);
      gload_lds16(Wz + (size_t)(n0 + c * 16 + srow) * DB + k0 + scol, &Bs[c * 512]);
    }
    __syncthreads();
    bf16x8 af[4], bf_[4];
#pragma unroll
    for (int i = 0; i < 4; i++)
      af[i] = *(const bf16x8*)&As[(wr * 64 + i * 16 + lrow) * 32 + lk * 8];
#pragma unroll
    for (int j = 0; j < 4; j++)
      bf_[j] = *(const bf16x8*)&Bs[(wc * 64 + j * 16 + lrow) * 32 + lk * 8];
#pragma unroll
    for (int i = 0; i < 4; i++)
#pragma unroll
      for (int j = 0; j < 4; j++)
        acc[i][j] = __builtin_amdgcn_mfma_f32_16x16x32_bf16(af[i], bf_[j], acc[i][j], 0, 0, 0);
    __syncthreads();
  }

#pragma unroll
  for (int j = 0; j < 4; j++) {
    int n = n0 + wc * 64 + j * 16 + lrow;
    float bb = bv[n];
    int h = n >> 6, hd = n & 63;
#pragma unroll
    for (int i = 0; i < 4; i++) {
      int mbase = m0 + wr * 64 + i * 16 + lk * 4;
      int b = mbase >> 11;
      int s = mbase & (SB - 1);
      int bh = b * NH + h;
      u16x4 pk;
#pragma unroll
      for (int r = 0; r < 4; r++) pk[r] = f2bf(acc[i][j][r] + bb);
      size_t idx = ((size_t)bh * HD + hd) * SB + (s & ~63) + ((s & 63) ^ ((hd & 7) << 3));
      *(u16x4*)&V[idx] = pk;
    }
  }
}

// ---- flash attention: QBLK=128, 8 waves, K/V LDS-staged (dbuf), swapped QK^T,
// bias as MFMA C-init, l via all-ones MFMA ----
// grid (NH, B*16); block 512
__global__ __launch_bounds__(512) void attn_kernel(
    const u16* __restrict__ Q, const u16* __restrict__ K, const u16* __restrict__ Vt,
    const u16* __restrict__ biasR, float* __restrict__ out) {
  __shared__ __align__(16) u16 Klds[2][4096];
  __shared__ __align__(16) u16 Vlds[2][4096];
  __shared__ __align__(16) u16 P[8][1024];
  int h = blockIdx.x;
  int b = blockIdx.y >> 4, q0b = blockIdx.y & 15;
  int bh = b * NH + h;
  int q0 = q0b * 128;
  int tid = threadIdx.x, wid = tid >> 6, lane = tid & 63;
  int lrow = lane & 15, lk = lane >> 4;
  const u16* Qb = Q + (size_t)bh * SB * HD;
  const u16* Kb = K + (size_t)bh * SB * HD;
  const u16* Vb = Vt + (size_t)bh * HD * SB;
  const u16* biasW = biasR + ((((size_t)b * 16 + q0b) * 32) * 8 + wid) * 1024 + lane * 16;

  int qr = q0 + wid * 16 + lrow;
  bf16x8 qf0 = *(const bf16x8*)&Qb[(size_t)qr * HD + lk * 8];
  bf16x8 qf1 = *(const bf16x8*)&Qb[(size_t)qr * HD + 32 + lk * 8];

  const bf16x8 vones = {0x3F80, 0x3F80, 0x3F80, 0x3F80, 0x3F80, 0x3F80, 0x3F80, 0x3F80};

  int kst = wid * 512 + lane * 8;
  int vrow_st = wid * 8 + (lane >> 3), vslot = lane & 7;

  f32x4 acc[4], accl;
#pragma unroll
  for (int d = 0; d < 4; d++) acc[d] = (f32x4){0.f, 0.f, 0.f, 0.f};
  accl = (f32x4){0.f, 0.f, 0.f, 0.f};
  u16* Pw = &P[wid][0];

  // prologue: stage tile 0 into buf 0
  gload_lds16(Kb + kst, &Klds[0][wid * 512]);
  gload_lds16(Vb + (size_t)vrow_st * SB + vslot * 8, &Vlds[0][wid * 512]);
  u16x8 bc0 = *(const u16x8*)biasW;
  u16x8 bc1 = *(const u16x8*)(biasW + 8);
  __syncthreads();

#pragma unroll 2
  for (int ktb = 0; ktb < 32; ktb++) {
    int cur = ktb & 1;
    if (ktb < 31) {
      int ktn = (ktb + 1) * 64;
      gload_lds16(Kb + (size_t)ktn * HD + kst, &Klds[cur ^ 1][wid * 512]);
      gload_lds16(Vb + (size_t)vrow_st * SB + ktn + vslot * 8, &Vlds[cur ^ 1][wid * 512]);
    }
    // prefetch next tile's bias
    int ktp = (ktb + 1) & 31;
    u16x8 bn0 = *(const u16x8*)(biasW + (size_t)ktp * 8192);
    u16x8 bn1 = *(const u16x8*)(biasW + (size_t)ktp * 8192 + 8);

    // unpack current bias into f32 C-init fragments
    f32x4 bf[4];
#pragma unroll
    for (int kb = 0; kb < 4; kb++)
#pragma unroll
      for (int r = 0; r < 4; r++) {
        int e = kb * 4 + r;
        bf[kb][r] = bf2f(e < 8 ? bc0[e] : bc1[e - 8]);
      }

    // swapped QK^T with bias C-init: lane holds q=lrow, k = kb*16 + lk*4 + r
    f32x4 s[4];
    __builtin_amdgcn_s_setprio(1);
#pragma unroll
    for (int kb = 0; kb < 4; kb++) {
      int krow = kb * 16 + lrow;
      int sw = (krow & 7) << 3;
      bf16x8 ka0 = *(const bf16x8*)&Klds[cur][krow * 64 + ((lk * 8) ^ sw)];
      bf16x8 ka1 = *(const bf16x8*)&Klds[cur][krow * 64 + ((32 + lk * 8) ^ sw)];
      f32x4 t = __builtin_amdgcn_mfma_f32_16x16x32_bf16(ka0, qf0, bf[kb], 0, 0, 0);
      s[kb] = __builtin_amdgcn_mfma_f32_16x16x32_bf16(ka1, qf1, t, 0, 0, 0);
    }
    __builtin_amdgcn_s_setprio(0);

    // exp2 directly (bias already inside), pack, LDS write
#pragma unroll
    for (int kb = 0; kb < 4; kb++) {
      float pv0 = exp2f(s[kb][0]), pv1 = exp2f(s[kb][1]);
      float pv2 = exp2f(s[kb][2]), pv3 = exp2f(s[kb][3]);
      unsigned d0 = cvt_pk_bf16(pv0, pv1);
      unsigned d1 = cvt_pk_bf16(pv2, pv3);
      int byte = (lrow * 128 + kb * 32 + lk * 8) ^ ((lrow & 7) << 4);
      *(uint2*)((char*)Pw + byte) = make_uint2(d0, d1);
    }
    bc0 = bn0; bc1 = bn1;
    asm volatile("s_waitcnt lgkmcnt(0)" ::: "memory");

    // PV + l: A = P from LDS (row=q=lrow), B = V from Vlds / all-ones
    bf16x8 pa[2];
#pragma unroll
    for (int ks = 0; ks < 2; ks++) {
      int byte = (lrow * 128 + ks * 64 + lk * 16) ^ ((lrow & 7) << 4);
      pa[ks] = *(const bf16x8*)((char*)Pw + byte);
    }
    __builtin_amdgcn_s_setprio(1);
    accl = __builtin_amdgcn_mfma_f32_16x16x32_bf16(pa[0], vones, accl, 0, 0, 0);
    accl = __builtin_amdgcn_mfma_f32_16x16x32_bf16(pa[1], vones, accl, 0, 0, 0);
#pragma unroll
    for (int db = 0; db < 4; db++) {
      int vrow = db * 16 + lrow;
      int sw = (vrow & 7) << 3;
#pragma unroll
      for (int ks = 0; ks < 2; ks++) {
        bf16x8 vb = *(const bf16x8*)&Vlds[cur][vrow * 64 + ((ks * 32 + lk * 8) ^ sw)];
        acc[db] = __builtin_amdgcn_mfma_f32_16x16x32_bf16(pa[ks], vb, acc[db], 0, 0, 0);
      }
    }
    __builtin_amdgcn_s_setprio(0);
    __syncthreads();
  }

  // epilogue: lane holds D[q = lk*4 + r][d = db*16 + lrow]; accl[r] = l[q]
  float inv[4];
#pragma unroll
  for (int r = 0; r < 4; r++) inv[r] = 1.0f / accl[r];
#pragma unroll
  for (int db = 0; db < 4; db++) {
#pragma unroll
    for (int r = 0; r < 4; r++) {
      int qg = q0 + wid * 16 + lk * 4 + r;
      out[((size_t)b * SB + qg) * DB + h * HD + db * 16 + lrow] = acc[db][r] * inv[r];
    }
  }
}

extern "C" void kernel_launch(void* const* d_in, const int* in_sizes, int n_in,
                              void* d_out, int out_size, void* d_ws, size_t ws_size,
                              hipStream_t stream) {
  const float* hs    = (const float*)d_in[0];
  const float* mask  = (const float*)d_in[1];
  const float* biasM = (const float*)d_in[2];
  const float* coef  = (const float*)d_in[3];
  const float* Wq    = (const float*)d_in[4];
  const float* bq    = (const float*)d_in[5];
  const float* Wk    = (const float*)d_in[6];
  const float* bk    = (const float*)d_in[7];
  const float* Wv    = (const float*)d_in[8];
  const float* bv    = (const float*)d_in[9];
  float* out = (float*)d_out;

  // workspace layout (40 MB): biasR overlaps X/Wt (biasR written after gemm)
  char* w = (char*)d_ws;
  u16* Qb    = (u16*)(w);                       // [32][2048][64]  (8 MB)
  u16* Kb    = (u16*)(w + 8u * 1024 * 1024);    // [32][2048][64] swizzled (8 MB)
  u16* Vb    = (u16*)(w + 16u * 1024 * 1024);   // [32][64][2048] swizzled (8 MB)
  u16* X     = (u16*)(w + 24u * 1024 * 1024);   // 4096x1024 bf16  (8 MB)
  u16* Wt    = (u16*)(w + 32u * 1024 * 1024);   // 3x1024x1024     (6 MB)
  u16* biasR = (u16*)(w + 24u * 1024 * 1024);   // [2][16][32][8][64][16] (16 MB)

  conv_x_kernel<<<2048, 256, 0, stream>>>(hs, X);
  conv_wt_kernel<<<dim3(32, 32, 3), dim3(32, 8), 0, stream>>>(Wq, Wk, Wv, Wt);
  gemm_qk_kernel<<<dim3(32, 8, 2), 256, 0, stream>>>(X, Wt, bq, bk, Qb, Kb);
  gemm_v_kernel<<<dim3(32, 8, 1), 256, 0, stream>>>(X, Wt, bv, Vb);
  conv_biasr_kernel<<<dim3(32, 32, 2), 256, 0, stream>>>(biasM, coef, mask, biasR);
  attn_kernel<<<dim3(NH, 32), 512, 0, stream>>>(Qb, Kb, Vb, biasR, out);
}

// Round 11
// 223.614 us; speedup vs baseline: 1.7678x; 1.0161x over previous
//
#include <hip/hip_runtime.h>

typedef unsigned short u16;
typedef __attribute__((ext_vector_type(8))) short bf16x8;
typedef __attribute__((ext_vector_type(4))) float f32x4;
typedef __attribute__((ext_vector_type(8))) unsigned short u16x8;
typedef __attribute__((ext_vector_type(4))) unsigned short u16x4;
typedef __attribute__((ext_vector_type(4))) float f32x4v;

#define LOG2E 1.4426950408889634f
#define QSCALE 0.18033688011112042f  // 0.125 * log2(e)

// B=2, S=2048, D=1024, H=16, HD=64
#define SB 2048
#define DB 1024
#define NH 16
#define HD 64

__device__ __forceinline__ u16 f2bf(float f) {
  unsigned u = __float_as_uint(f);
  return (u16)((u + 0x7FFFu + ((u >> 16) & 1u)) >> 16);
}
__device__ __forceinline__ float bf2f(u16 h) {
  return __uint_as_float(((unsigned)h) << 16);
}
__device__ __forceinline__ unsigned cvt_pk_bf16(float lo, float hi) {
  unsigned r;
  asm("v_cvt_pk_bf16_f32 %0, %1, %2" : "=v"(r) : "v"(lo), "v"(hi));
  return r;
}

__device__ __forceinline__ void gload_lds16(const void* g, void* l) {
  __builtin_amdgcn_global_load_lds((const __attribute__((address_space(1))) void*)g,
                                   (__attribute__((address_space(3))) void*)l, 16, 0, 0);
}

// ---- conversion kernels ----

__global__ void conv_x_kernel(const float* __restrict__ in, u16* __restrict__ out) {
  int i = blockIdx.x * blockDim.x + threadIdx.x;  // each handles 8 elems
  const f32x4v* p = (const f32x4v*)in + (size_t)i * 2;
  f32x4v a = p[0], b = p[1];
  u16x8 o;
  o[0] = f2bf(a[0]); o[1] = f2bf(a[1]); o[2] = f2bf(a[2]); o[3] = f2bf(a[3]);
  o[4] = f2bf(b[0]); o[5] = f2bf(b[1]); o[6] = f2bf(b[2]); o[7] = f2bf(b[3]);
  *((u16x8*)out + i) = o;
}

// transpose W [K][N] -> Wt [N][K] in bf16, z selects Wq/Wk/Wv
__global__ void conv_wt_kernel(const float* __restrict__ Wq, const float* __restrict__ Wk,
                               const float* __restrict__ Wv, u16* __restrict__ Wt) {
  __shared__ float tile[32][33];
  int z = blockIdx.z;
  const float* W = (z == 0) ? Wq : (z == 1) ? Wk : Wv;
  int k0 = blockIdx.x * 32, n0 = blockIdx.y * 32;
  int tx = threadIdx.x;
  for (int i = threadIdx.y; i < 32; i += 8)
    tile[i][tx] = W[(size_t)(k0 + i) * DB + n0 + tx];
  __syncthreads();
  for (int i = threadIdx.y; i < 32; i += 8)
    Wt[(size_t)z * DB * DB + (size_t)(n0 + i) * DB + k0 + tx] = f2bf(tile[tx][i]);
}

// Bias rearranged for attn (QBLK=128, 8 waves): bf16, pre-scaled by coef*LOG2E,
// mask folded in. Layout [b][q0b:16][ktb:32][wid:8][lane:64][16].
__global__ __launch_bounds__(256) void conv_biasr_kernel(
    const float* __restrict__ biasM, const float* __restrict__ coef,
    const float* __restrict__ mask, u16* __restrict__ biasR) {
  __shared__ float tile[64 * 64];
  __shared__ float msh[64];
  int ktb = blockIdx.x, q64b = blockIdx.y, b = blockIdx.z;
  int q0 = q64b * 64, k0 = ktb * 64;
  int tid = threadIdx.x;
  float c = coef[0] * LOG2E;
  for (int i = tid; i < 4096; i += 256)
    tile[i] = biasM[(size_t)(q0 + (i >> 6)) * SB + k0 + (i & 63)];
  if (tid < 64) msh[tid] = mask[b * SB + k0 + tid] * LOG2E;
  __syncthreads();
  int wid = tid >> 6, lane = tid & 63, lrow = lane & 15, lk = lane >> 4;
  int qloc = wid * 16 + lrow;
  u16x8 o0, o1;
#pragma unroll
  for (int e = 0; e < 16; e++) {
    int kloc = (e >> 2) * 16 + lk * 4 + (e & 3);
    float v = tile[qloc * 64 + kloc] * c + msh[kloc];
    if (e < 8) o0[e] = f2bf(v); else o1[e - 8] = f2bf(v);
  }
  int widp = (q64b & 1) * 4 + wid;
  size_t base = ((((size_t)b * 16 + (q64b >> 1)) * 32 + ktb) * 8 + widp) * 1024 + lane * 16;
  *(u16x8*)&biasR[base] = o0;
  *(u16x8*)&biasR[base + 8] = o1;
}

// ---- merged QKV projection GEMM (z: 0=Q swapped, 1=K swapped, 2=V) ----
// Q (scaled) plain [bh][s][64]; K swizzled hd' = hd ^ ((s&7)<<3);
// V d-major [bh][64][2048], swizzled s' = (s&~63) + ((s&63)^((hd&7)<<3))
__global__ __launch_bounds__(256) void gemm_qkv_kernel(
    const u16* __restrict__ X, const u16* __restrict__ Wt,
    const float* __restrict__ bq, const float* __restrict__ bk, const float* __restrict__ bv,
    u16* __restrict__ Q, u16* __restrict__ K, u16* __restrict__ V) {
  __shared__ __align__(16) u16 As[128 * 32];
  __shared__ __align__(16) u16 Bs[128 * 32];
  int z = blockIdx.z;
  const u16* Wz = Wt + (size_t)z * DB * DB;
  int m0 = blockIdx.x * 128, n0 = blockIdx.y * 128;
  int tid = threadIdx.x, wid = tid >> 6, lane = tid & 63;
  int wr = wid >> 1, wc = wid & 1;
  int lrow = lane & 15, lk = lane >> 4;
  int srow = lane >> 2, scol = (lane & 3) * 8;

  f32x4 acc[4][4];
#pragma unroll
  for (int i = 0; i < 4; i++)
#pragma unroll
    for (int j = 0; j < 4; j++) acc[i][j] = (f32x4){0.f, 0.f, 0.f, 0.f};

  if (z < 2) {
    // swapped operands: lane holds D[n..n+3][m]
    for (int k0 = 0; k0 < DB; k0 += 32) {
#pragma unroll
      for (int p = 0; p < 2; p++) {
        int c = p * 4 + wid;
        gload_lds16(X + (size_t)(m0 + c * 16 + srow) * DB + k0 + scol, &As[c * 512]);
        gload_lds16(Wz + (size_t)(n0 + c * 16 + srow) * DB + k0 + scol, &Bs[c * 512]);
      }
      __syncthreads();
      bf16x8 af[4], bf_[4];
#pragma unroll
      for (int i = 0; i < 4; i++)
        af[i] = *(const bf16x8*)&As[(wr * 64 + i * 16 + lrow) * 32 + lk * 8];
#pragma unroll
      for (int j = 0; j < 4; j++)
        bf_[j] = *(const bf16x8*)&Bs[(wc * 64 + j * 16 + lrow) * 32 + lk * 8];
#pragma unroll
      for (int i = 0; i < 4; i++)
#pragma unroll
        for (int j = 0; j < 4; j++)
          acc[i][j] = __builtin_amdgcn_mfma_f32_16x16x32_bf16(bf_[j], af[i], acc[i][j], 0, 0, 0);
      __syncthreads();
    }
    const float* bias = (z == 0) ? bq : bk;
    u16* dst = (z == 0) ? Q : K;
    int h = (n0 >> 6) + wc;
#pragma unroll
    for (int j = 0; j < 4; j++) {
      int nb = wc * 64 + j * 16 + lk * 4;
      f32x4v bb4 = *(const f32x4v*)&bias[n0 + nb];
      int hd0 = nb & 63;
#pragma unroll
      for (int i = 0; i < 4; i++) {
        int m = m0 + wr * 64 + i * 16 + lrow;
        int b = m >> 11, s = m & (SB - 1);
        int bh = b * NH + h;
        u16x4 pk;
        if (z == 0) {
#pragma unroll
          for (int r = 0; r < 4; r++) pk[r] = f2bf((acc[i][j][r] + bb4[r]) * QSCALE);
          *(u16x4*)&dst[((size_t)bh * SB + s) * HD + hd0] = pk;
        } else {
#pragma unroll
          for (int r = 0; r < 4; r++) pk[r] = f2bf(acc[i][j][r] + bb4[r]);
          *(u16x4*)&dst[((size_t)bh * SB + s) * HD + (hd0 ^ ((s & 7) << 3))] = pk;
        }
      }
    }
  } else {
    // V: normal operands, lane holds D[m..m+3][n] -> 4 consecutive s at fixed hd
    for (int k0 = 0; k0 < DB; k0 += 32) {
#pragma unroll
      for (int p = 0; p < 2; p++) {
        int c = p * 4 + wid;
        gload_lds16(X + (size_t)(m0 + c * 16 + srow) * DB + k0 + scol, &As[c * 512]);
        gload_lds16(Wz + (size_t)(n0 + c * 16 + srow) * DB + k0 + scol, &Bs[c * 512]);
      }
      __syncthreads();
      bf16x8 af[4], bf_[4];
#pragma unroll
      for (int i = 0; i < 4; i++)
        af[i] = *(const bf16x8*)&As[(wr * 64 + i * 16 + lrow) * 32 + lk * 8];
#pragma unroll
      for (int j = 0; j < 4; j++)
        bf_[j] = *(const bf16x8*)&Bs[(wc * 64 + j * 16 + lrow) * 32 + lk * 8];
#pragma unroll
      for (int i = 0; i < 4; i++)
#pragma unroll
        for (int j = 0; j < 4; j++)
          acc[i][j] = __builtin_amdgcn_mfma_f32_16x16x32_bf16(af[i], bf_[j], acc[i][j], 0, 0, 0);
      __syncthreads();
    }
#pragma unroll
    for (int j = 0; j < 4; j++) {
      int n = n0 + wc * 64 + j * 16 + lrow;
      float bb = bv[n];
      int h = n >> 6, hd = n & 63;
#pragma unroll
      for (int i = 0; i < 4; i++) {
        int mbase = m0 + wr * 64 + i * 16 + lk * 4;
        int b = mbase >> 11;
        int s = mbase & (SB - 1);
        int bh = b * NH + h;
        u16x4 pk;
#pragma unroll
        for (int r = 0; r < 4; r++) pk[r] = f2bf(acc[i][j][r] + bb);
        size_t idx = ((size_t)bh * HD + hd) * SB + (s & ~63) + ((s & 63) ^ ((hd & 7) << 3));
        *(u16x4*)&V[idx] = pk;
      }
    }
  }
}

// ---- flash attention: QBLK=128, 8 waves, K/V LDS dbuf, swapped QK^T,
// bias C-init, l via all-ones MFMA, counted-vmcnt 2-phase schedule ----
// grid (NH, B*16); block 512

// One K-tile phase. CUR is a literal (0/1); C0/C1 = this tile's bias regs;
// N0/N1 = regs the next tile's bias is loaded into (no copies).
#define ATTN_PHASE(CUR, KTB, C0, C1, N0, N1)                                          \
  {                                                                                   \
    int ktb_ = (KTB);                                                                 \
    int kt_ = ktb_ * 64;                                                              \
    if (ktb_ < 31) {                                                                  \
      gload_lds16(Kb + (size_t)(kt_ + 64) * HD + kst, &Klds[(CUR) ^ 1][wid * 512]);   \
      gload_lds16(Vb + (size_t)vrow_st * SB + kt_ + 64 + vslot * 8,                   \
                  &Vlds[(CUR) ^ 1][wid * 512]);                                       \
    }                                                                                 \
    int ktp_ = (ktb_ + 1) & 31;                                                       \
    N0 = *(const u16x8*)(biasW + (size_t)ktp_ * 8192);                                \
    N1 = *(const u16x8*)(biasW + (size_t)ktp_ * 8192 + 8);                            \
    f32x4 bf_[4];                                                                     \
    _Pragma("unroll") for (int kb = 0; kb < 4; kb++)                                  \
        _Pragma("unroll") for (int r = 0; r < 4; r++) {                               \
      int e = kb * 4 + r;                                                             \
      bf_[kb][r] = bf2f(e < 8 ? C0[e] : C1[e - 8]);                                   \
    }                                                                                 \
    f32x4 s_[4];                                                                      \
    __builtin_amdgcn_s_setprio(1);                                                    \
    _Pragma("unroll") for (int kb = 0; kb < 4; kb++) {                                \
      int krow = kb * 16 + lrow;                                                      \
      int sw = (krow & 7) << 3;                                                       \
      bf16x8 ka0 = *(const bf16x8*)&Klds[CUR][krow * 64 + ((lk * 8) ^ sw)];           \
      bf16x8 ka1 = *(const bf16x8*)&Klds[CUR][krow * 64 + ((32 + lk * 8) ^ sw)];      \
      f32x4 t_ = __builtin_amdgcn_mfma_f32_16x16x32_bf16(ka0, qf0, bf_[kb], 0, 0, 0); \
      s_[kb] = __builtin_amdgcn_mfma_f32_16x16x32_bf16(ka1, qf1, t_, 0, 0, 0);        \
    }                                                                                 \
    __builtin_amdgcn_s_setprio(0);                                                    \
    _Pragma("unroll") for (int kb = 0; kb < 4; kb++) {                                \
      float pv0 = exp2f(s_[kb][0]), pv1 = exp2f(s_[kb][1]);                           \
      float pv2 = exp2f(s_[kb][2]), pv3 = exp2f(s_[kb][3]);                           \
      unsigned d0 = cvt_pk_bf16(pv0, pv1);                                            \
      unsigned d1 = cvt_pk_bf16(pv2, pv3);                                            \
      int byte = (lrow * 128 + kb * 32 + lk * 8) ^ ((lrow & 7) << 4);                 \
      *(uint2*)((char*)Pw + byte) = make_uint2(d0, d1);                               \
    }                                                                                 \
    asm volatile("s_waitcnt lgkmcnt(0)" ::: "memory");                                \
    bf16x8 pa0, pa1;                                                                  \
    {                                                                                 \
      int b0 = (lrow * 128 + lk * 16) ^ ((lrow & 7) << 4);                            \
      int b1 = (lrow * 128 + 64 + lk * 16) ^ ((lrow & 7) << 4);                       \
      pa0 = *(const bf16x8*)((char*)Pw + b0);                                         \
      pa1 = *(const bf16x8*)((char*)Pw + b1);                                         \
    }                                                                                 \
    __builtin_amdgcn_s_setprio(1);                                                    \
    accl = __builtin_amdgcn_mfma_f32_16x16x32_bf16(pa0, vones, accl, 0, 0, 0);        \
    accl = __builtin_amdgcn_mfma_f32_16x16x32_bf16(pa1, vones, accl, 0, 0, 0);        \
    _Pragma("unroll") for (int db = 0; db < 4; db++) {                                \
      int vrow = db * 16 + lrow;                                                      \
      int sw = (vrow & 7) << 3;                                                       \
      bf16x8 vb0 = *(const bf16x8*)&Vlds[CUR][vrow * 64 + ((lk * 8) ^ sw)];           \
      bf16x8 vb1 = *(const bf16x8*)&Vlds[CUR][vrow * 64 + ((32 + lk * 8) ^ sw)];      \
      acc[db] = __builtin_amdgcn_mfma_f32_16x16x32_bf16(pa0, vb0, acc[db], 0, 0, 0);  \
      acc[db] = __builtin_amdgcn_mfma_f32_16x16x32_bf16(pa1, vb1, acc[db], 0, 0, 0);  \
    }                                                                                 \
    __builtin_amdgcn_s_setprio(0);                                                    \
    asm volatile("s_waitcnt vmcnt(2)" ::: "memory");                                  \
    __builtin_amdgcn_s_barrier();                                                     \
    __builtin_amdgcn_sched_barrier(0);                                                \
  }

__global__ __launch_bounds__(512) void attn_kernel(
    const u16* __restrict__ Q, const u16* __restrict__ K, const u16* __restrict__ Vt,
    const u16* __restrict__ biasR, float* __restrict__ out) {
  __shared__ __align__(16) u16 Klds[2][4096];
  __shared__ __align__(16) u16 Vlds[2][4096];
  __shared__ __align__(16) u16 P[8][1024];
  int h = blockIdx.x;
  int b = blockIdx.y >> 4, q0b = blockIdx.y & 15;
  int bh = b * NH + h;
  int q0 = q0b * 128;
  int tid = threadIdx.x, wid = tid >> 6, lane = tid & 63;
  int lrow = lane & 15, lk = lane >> 4;
  const u16* Qb = Q + (size_t)bh * SB * HD;
  const u16* Kb = K + (size_t)bh * SB * HD;
  const u16* Vb = Vt + (size_t)bh * HD * SB;
  const u16* biasW = biasR + ((((size_t)b * 16 + q0b) * 32) * 8 + wid) * 1024 + lane * 16;

  int qr = q0 + wid * 16 + lrow;
  bf16x8 qf0 = *(const bf16x8*)&Qb[(size_t)qr * HD + lk * 8];
  bf16x8 qf1 = *(const bf16x8*)&Qb[(size_t)qr * HD + 32 + lk * 8];

  const bf16x8 vones = {0x3F80, 0x3F80, 0x3F80, 0x3F80, 0x3F80, 0x3F80, 0x3F80, 0x3F80};

  int kst = wid * 512 + lane * 8;
  int vrow_st = wid * 8 + (lane >> 3), vslot = lane & 7;

  f32x4 acc[4], accl;
#pragma unroll
  for (int d = 0; d < 4; d++) acc[d] = (f32x4){0.f, 0.f, 0.f, 0.f};
  accl = (f32x4){0.f, 0.f, 0.f, 0.f};
  u16* Pw = &P[wid][0];

  // prologue: stage tile 0 into buf 0; load tile-0 bias
  gload_lds16(Kb + kst, &Klds[0][wid * 512]);
  gload_lds16(Vb + (size_t)vrow_st * SB + vslot * 8, &Vlds[0][wid * 512]);
  u16x8 bA0 = *(const u16x8*)biasW;
  u16x8 bA1 = *(const u16x8*)(biasW + 8);
  u16x8 bB0, bB1;
  __syncthreads();

  for (int it = 0; it < 16; ++it) {
    ATTN_PHASE(0, it * 2, bA0, bA1, bB0, bB1);
    ATTN_PHASE(1, it * 2 + 1, bB0, bB1, bA0, bA1);
  }

  // epilogue: lane holds D[q = lk*4 + r][d = db*16 + lrow]; accl[r] = l[q]
  float inv[4];
#pragma unroll
  for (int r = 0; r < 4; r++) inv[r] = 1.0f / accl[r];
#pragma unroll
  for (int db = 0; db < 4; db++) {
#pragma unroll
    for (int r = 0; r < 4; r++) {
      int qg = q0 + wid * 16 + lk * 4 + r;
      out[((size_t)b * SB + qg) * DB + h * HD + db * 16 + lrow] = acc[db][r] * inv[r];
    }
  }
}

extern "C" void kernel_launch(void* const* d_in, const int* in_sizes, int n_in,
                              void* d_out, int out_size, void* d_ws, size_t ws_size,
                              hipStream_t stream) {
  const float* hs    = (const float*)d_in[0];
  const float* mask  = (const float*)d_in[1];
  const float* biasM = (const float*)d_in[2];
  const float* coef  = (const float*)d_in[3];
  const float* Wq    = (const float*)d_in[4];
  const float* bq    = (const float*)d_in[5];
  const float* Wk    = (const float*)d_in[6];
  const float* bk    = (const float*)d_in[7];
  const float* Wv    = (const float*)d_in[8];
  const float* bv    = (const float*)d_in[9];
  float* out = (float*)d_out;

  // workspace layout (40 MB): biasR overlaps X/Wt (biasR written after gemm)
  char* w = (char*)d_ws;
  u16* Qb    = (u16*)(w);                       // [32][2048][64]  (8 MB)
  u16* Kb    = (u16*)(w + 8u * 1024 * 1024);    // [32][2048][64] swizzled (8 MB)
  u16* Vb    = (u16*)(w + 16u * 1024 * 1024);   // [32][64][2048] swizzled (8 MB)
  u16* X     = (u16*)(w + 24u * 1024 * 1024);   // 4096x1024 bf16  (8 MB)
  u16* Wt    = (u16*)(w + 32u * 1024 * 1024);   // 3x1024x1024     (6 MB)
  u16* biasR = (u16*)(w + 24u * 1024 * 1024);   // [2][16][32][8][64][16] (16 MB)

  conv_x_kernel<<<2048, 256, 0, stream>>>(hs, X);
  conv_wt_kernel<<<dim3(32, 32, 3), dim3(32, 8), 0, stream>>>(Wq, Wk, Wv, Wt);
  gemm_qkv_kernel<<<dim3(32, 8, 3), 256, 0, stream>>>(X, Wt, bq, bk, bv, Qb, Kb, Vb);
  conv_biasr_kernel<<<dim3(32, 32, 2), 256, 0, stream>>>(biasM, coef, mask, biasR);
  attn_kernel<<<dim3(NH, 32), 512, 0, stream>>>(Qb, Kb, Vb, biasR, out);
}